// Round 1
// 464.189 us; speedup vs baseline: 1.0255x; 1.0255x over previous
//
#include <hip/hip_runtime.h>
#include <hip/hip_bf16.h>
#include <math.h>
#include <stdint.h>

// Problem constants
#define BB 2
#define TT 2048
#define DD 1024
#define HH 16
#define DK 64
#define HD 1024   // H*DK
#define NC 32     // chunks per sequence (TT/64)
#define CL 64     // chunk length
#define PAD 68    // padded LDS row stride (floats) to break stride-64 bank conflicts
#define VS 16     // v-splits in hrec_k

typedef short bf16x8 __attribute__((ext_vector_type(8)));     // 8 bf16 (4 VGPRs)
typedef float f32x4 __attribute__((ext_vector_type(4)));      // MFMA acc
typedef unsigned short u16x8 __attribute__((ext_vector_type(8)));
typedef unsigned short u16x4 __attribute__((ext_vector_type(4)));

#define GAS __attribute__((address_space(1)))
#define LAS __attribute__((address_space(3)))

#define DOT4(a, b) ((a).x*(b).x + (a).y*(b).y + (a).z*(b).z + (a).w*(b).w)

// acc[i][j] += kf[i-component] * wv[j-component]   (one contraction step)
#define OUT16(acc, kf, wv) \
    acc[0][0] += kf.x * wv.x; acc[0][1] += kf.x * wv.y; acc[0][2] += kf.x * wv.z; acc[0][3] += kf.x * wv.w; \
    acc[1][0] += kf.y * wv.x; acc[1][1] += kf.y * wv.y; acc[1][2] += kf.y * wv.z; acc[1][3] += kf.y * wv.w; \
    acc[2][0] += kf.z * wv.x; acc[2][1] += kf.z * wv.y; acc[2][2] += kf.z * wv.z; acc[2][3] += kf.z * wv.w; \
    acc[3][0] += kf.w * wv.x; acc[3][1] += kf.w * wv.y; acc[3][2] += kf.w * wv.z; acc[3][3] += kf.w * wv.w;

// acc[i][j] -= wa_i.c * hv[j]   (c = component selecting m)
#define WSUB(c, hv) \
    acc[0][0] -= wa0.c * hv.x; acc[0][1] -= wa0.c * hv.y; acc[0][2] -= wa0.c * hv.z; acc[0][3] -= wa0.c * hv.w; \
    acc[1][0] -= wa1.c * hv.x; acc[1][1] -= wa1.c * hv.y; acc[1][2] -= wa1.c * hv.z; acc[1][3] -= wa1.c * hv.w; \
    acc[2][0] -= wa2.c * hv.x; acc[2][1] -= wa2.c * hv.y; acc[2][2] -= wa2.c * hv.z; acc[2][3] -= wa2.c * hv.w; \
    acc[3][0] -= wa3.c * hv.x; acc[3][1] -= wa3.c * hv.y; acc[3][2] -= wa3.c * hv.z; acc[3][3] -= wa3.c * hv.w;

// acc[i][j] += sa_i.c * wv[j]   (c = component selecting the contraction idx)
#define ACC16(c, wv) \
    acc[0][0] += sa0.c * wv.x; acc[0][1] += sa0.c * wv.y; acc[0][2] += sa0.c * wv.z; acc[0][3] += sa0.c * wv.w; \
    acc[1][0] += sa1.c * wv.x; acc[1][1] += sa1.c * wv.y; acc[1][2] += sa1.c * wv.z; acc[1][3] += sa1.c * wv.w; \
    acc[2][0] += sa2.c * wv.x; acc[2][1] += sa2.c * wv.y; acc[2][2] += sa2.c * wv.z; acc[2][3] += sa2.c * wv.w; \
    acc[3][0] += sa3.c * wv.x; acc[3][1] += sa3.c * wv.y; acc[3][2] += sa3.c * wv.z; acc[3][3] += sa3.c * wv.w;

__device__ __forceinline__ float sigmoidf_(float x) { return 1.0f / (1.0f + expf(-x)); }
__device__ __forceinline__ float siluf_(float x) { return x * sigmoidf_(x); }

// round-to-nearest-even fp32 -> bf16
__device__ __forceinline__ unsigned short f2bf(float f) {
    unsigned int u = __builtin_bit_cast(unsigned int, f);
    u = (u + 0x7fffu + ((u >> 16) & 1u)) >> 16;
    return (unsigned short)u;
}

// ---------------------------------------------------------------------------
// Cast x (fp32) -> bf16, flat.
// ---------------------------------------------------------------------------
__global__ __launch_bounds__(256) void castx_k(const float* __restrict__ src,
                                               unsigned short* __restrict__ dst) {
    const size_t idx = (size_t)blockIdx.x * 256 + threadIdx.x;
    float4 a = *(const float4*)&src[idx * 8];
    float4 b = *(const float4*)&src[idx * 8 + 4];
    u16x8 o;
    o[0] = f2bf(a.x); o[1] = f2bf(a.y); o[2] = f2bf(a.z); o[3] = f2bf(a.w);
    o[4] = f2bf(b.x); o[5] = f2bf(b.y); o[6] = f2bf(b.z); o[7] = f2bf(b.w);
    *(u16x8*)&dst[idx * 8] = o;
}

// ---------------------------------------------------------------------------
// Transpose+cast weight: W[K=1024][N=1024] fp32 -> Wt[N][K] bf16.
// ---------------------------------------------------------------------------
__global__ __launch_bounds__(256) void castw_k(const float* __restrict__ W,
                                               unsigned short* __restrict__ Wt) {
    __shared__ float t_s[64][65];
    const int tid = threadIdx.x;
    const int rr = tid >> 4;
    const int cc = tid & 15;
    const int r0 = blockIdx.y * 64;
    const int c0 = blockIdx.x * 64;
#pragma unroll
    for (int i = 0; i < 4; ++i) {
        const int row = rr + i * 16;
        float4 v = *(const float4*)&W[(size_t)(r0 + row) * 1024 + c0 + cc * 4];
        t_s[row][cc * 4 + 0] = v.x;
        t_s[row][cc * 4 + 1] = v.y;
        t_s[row][cc * 4 + 2] = v.z;
        t_s[row][cc * 4 + 3] = v.w;
    }
    __syncthreads();
#pragma unroll
    for (int i = 0; i < 4; ++i) {
        const int nr = rr + i * 16;
        u16x4 o;
#pragma unroll
        for (int d = 0; d < 4; ++d) o[d] = f2bf(t_s[cc * 4 + d][nr]);
        *(u16x4*)&Wt[(size_t)(c0 + nr) * 1024 + r0 + cc * 4] = o;
    }
}

// ---------------------------------------------------------------------------
// transpose Wa|Wb [1024][16] -> Wab_t [32][1024] fp32 (R8)
// ---------------------------------------------------------------------------
__global__ __launch_bounds__(256) void tw_k(const float* __restrict__ Wa,
                                            const float* __restrict__ Wb,
                                            float* __restrict__ Wt) {
    const int o = blockIdx.x;          // 0..31
    const int h = o & 15;
    const float* W = (o < 16) ? Wa : Wb;
    const int tid = threadIdx.x;
    float4 v;
    v.x = W[(size_t)(tid * 4 + 0) * HH + h];
    v.y = W[(size_t)(tid * 4 + 1) * HH + h];
    v.z = W[(size_t)(tid * 4 + 2) * HH + h];
    v.w = W[(size_t)(tid * 4 + 3) * HH + h];
    *(float4*)&Wt[(size_t)o * DD + tid * 4] = v;
}

// ---------------------------------------------------------------------------
// bf16 MFMA GEMM (m97 structure) — generic single-output (used for Wo).
// ---------------------------------------------------------------------------
__global__ __launch_bounds__(256) void gemm_bf16_k(const unsigned short* __restrict__ A,
                                                   const unsigned short* __restrict__ Bt,
                                                   float* __restrict__ C,
                                                   int M, int N, int Kd) {
    __shared__ unsigned short a_s[128 * 32];
    __shared__ unsigned short b_s[128 * 32];

    const int tid = threadIdx.x;
    const int wave = tid >> 6;
    const int lane = tid & 63;
    const int m0 = blockIdx.y * 128;
    const int n0 = blockIdx.x * 128;

    const int quad = lane >> 4;
    const int l16 = lane & 15;
    const int wr = wave >> 1;
    const int wc = wave & 1;

    const int srow = lane >> 2;
    const int sseg = lane & 3;

    f32x4 acc[4][4];
#pragma unroll
    for (int i = 0; i < 4; ++i)
#pragma unroll
        for (int j = 0; j < 4; ++j) acc[i][j] = (f32x4){0.f, 0.f, 0.f, 0.f};

    for (int k0 = 0; k0 < Kd; k0 += 32) {
        __syncthreads();
#pragma unroll
        for (int c = 0; c < 2; ++c) {
            const int region = wave * 2 + c;
            const int r0t = region * 16;
            const int ra = r0t + srow;
            const unsigned short* ga = A + (size_t)(m0 + ra) * Kd + k0 + sseg * 8;
            const unsigned short* gb = Bt + (size_t)(n0 + ra) * Kd + k0 + sseg * 8;
            __builtin_amdgcn_global_load_lds((const GAS unsigned int*)ga,
                                             (LAS unsigned int*)&a_s[r0t * 32], 16, 0, 0);
            __builtin_amdgcn_global_load_lds((const GAS unsigned int*)gb,
                                             (LAS unsigned int*)&b_s[r0t * 32], 16, 0, 0);
        }
        __syncthreads();

        bf16x8 af[4], bfr[4];
#pragma unroll
        for (int i = 0; i < 4; ++i)
            af[i] = *(const bf16x8*)&a_s[(wr * 64 + i * 16 + l16) * 32 + quad * 8];
#pragma unroll
        for (int j = 0; j < 4; ++j)
            bfr[j] = *(const bf16x8*)&b_s[(wc * 64 + j * 16 + l16) * 32 + quad * 8];
#pragma unroll
        for (int i = 0; i < 4; ++i)
#pragma unroll
            for (int j = 0; j < 4; ++j)
                acc[i][j] = __builtin_amdgcn_mfma_f32_16x16x32_bf16(af[i], bfr[j], acc[i][j], 0, 0, 0);
    }

#pragma unroll
    for (int i = 0; i < 4; ++i)
#pragma unroll
        for (int j = 0; j < 4; ++j) {
            const int col = n0 + wc * 64 + j * 16 + l16;
#pragma unroll
            for (int r = 0; r < 4; ++r) {
                const int row = m0 + wr * 64 + i * 16 + quad * 4 + r;
                C[(size_t)row * N + col] = acc[i][j][r];
            }
        }
}

// ---------------------------------------------------------------------------
// Fused QKVG projection GEMM (R10, unchanged). N=4096; each 128-wide n-block
// writes into ONE of the 4 outputs (n0>>10), local col stride 1024.
// ---------------------------------------------------------------------------
__global__ __launch_bounds__(256) void gemm_qkvg_k(const unsigned short* __restrict__ A,
                                                   const unsigned short* __restrict__ Bt,
                                                   float* __restrict__ Oq,
                                                   float* __restrict__ Ok,
                                                   float* __restrict__ Ov,
                                                   float* __restrict__ Og) {
    __shared__ unsigned short a_s[128 * 32];
    __shared__ unsigned short b_s[128 * 32];

    const int tid = threadIdx.x;
    const int wave = tid >> 6;
    const int lane = tid & 63;
    const int m0 = blockIdx.y * 128;
    const int n0 = blockIdx.x * 128;          // 0..4095

    const int quad = lane >> 4;
    const int l16 = lane & 15;
    const int wr = wave >> 1;
    const int wc = wave & 1;

    const int srow = lane >> 2;
    const int sseg = lane & 3;

    f32x4 acc[4][4];
#pragma unroll
    for (int i = 0; i < 4; ++i)
#pragma unroll
        for (int j = 0; j < 4; ++j) acc[i][j] = (f32x4){0.f, 0.f, 0.f, 0.f};

    for (int k0 = 0; k0 < DD; k0 += 32) {
        __syncthreads();
#pragma unroll
        for (int c = 0; c < 2; ++c) {
            const int region = wave * 2 + c;
            const int r0t = region * 16;
            const int ra = r0t + srow;
            const unsigned short* ga = A + (size_t)(m0 + ra) * DD + k0 + sseg * 8;
            const unsigned short* gb = Bt + (size_t)(n0 + ra) * DD + k0 + sseg * 8;
            __builtin_amdgcn_global_load_lds((const GAS unsigned int*)ga,
                                             (LAS unsigned int*)&a_s[r0t * 32], 16, 0, 0);
            __builtin_amdgcn_global_load_lds((const GAS unsigned int*)gb,
                                             (LAS unsigned int*)&b_s[r0t * 32], 16, 0, 0);
        }
        __syncthreads();

        bf16x8 af[4], bfr[4];
#pragma unroll
        for (int i = 0; i < 4; ++i)
            af[i] = *(const bf16x8*)&a_s[(wr * 64 + i * 16 + l16) * 32 + quad * 8];
#pragma unroll
        for (int j = 0; j < 4; ++j)
            bfr[j] = *(const bf16x8*)&b_s[(wc * 64 + j * 16 + l16) * 32 + quad * 8];
#pragma unroll
        for (int i = 0; i < 4; ++i)
#pragma unroll
            for (int j = 0; j < 4; ++j)
                acc[i][j] = __builtin_amdgcn_mfma_f32_16x16x32_bf16(af[i], bfr[j], acc[i][j], 0, 0, 0);
    }

    float* Cd = (n0 < 1024) ? Oq : (n0 < 2048) ? Ok : (n0 < 3072) ? Ov : Og;
    const int nl = n0 & 1023;
#pragma unroll
    for (int i = 0; i < 4; ++i)
#pragma unroll
        for (int j = 0; j < 4; ++j) {
            const int col = nl + wc * 64 + j * 16 + l16;
#pragma unroll
            for (int r = 0; r < 4; ++r) {
                const int row = m0 + wr * 64 + i * 16 + quad * 4 + r;
                Cd[(size_t)row * HD + col] = acc[i][j][r];
            }
        }
}

// ---------------------------------------------------------------------------
// g / beta kernel (R8, unchanged)
// ---------------------------------------------------------------------------
__global__ __launch_bounds__(256) void gbeta_k(const float* __restrict__ x,
                                               const float* __restrict__ Wt,
                                               const float* __restrict__ A_log,
                                               const float* __restrict__ dt_bias,
                                               float* __restrict__ g,
                                               float* __restrict__ beta) {
    __shared__ __align__(16) float xs[8][DD];
    const int r0 = blockIdx.x * 8;
    const int tid = threadIdx.x;

#pragma unroll
    for (int i = 0; i < 8; ++i) {
        const int f = tid + i * 256;
        const int r = f >> 8;
        const int col = (f & 255) * 4;
        *(float4*)&xs[r][col] = *(const float4*)&x[((size_t)r0 + r) * DD + col];
    }
    __syncthreads();

    const int out = tid >> 3;
    const int part = tid & 7;
    const int h = out & 15;
    const float* Wrow = Wt + (size_t)out * DD;

    float a0 = 0, a1 = 0, a2 = 0, a3 = 0, a4 = 0, a5 = 0, a6 = 0, a7 = 0;
#pragma unroll 4
    for (int i = 0; i < 32; ++i) {
        const int d = i * 32 + part * 4;
        const float4 wv = *(const float4*)&Wrow[d];
        float4 x0 = *(const float4*)&xs[0][d];
        float4 x1 = *(const float4*)&xs[1][d];
        float4 x2 = *(const float4*)&xs[2][d];
        float4 x3 = *(const float4*)&xs[3][d];
        float4 x4 = *(const float4*)&xs[4][d];
        float4 x5 = *(const float4*)&xs[5][d];
        float4 x6 = *(const float4*)&xs[6][d];
        float4 x7 = *(const float4*)&xs[7][d];
        a0 += DOT4(x0, wv); a1 += DOT4(x1, wv);
        a2 += DOT4(x2, wv); a3 += DOT4(x3, wv);
        a4 += DOT4(x4, wv); a5 += DOT4(x5, wv);
        a6 += DOT4(x6, wv); a7 += DOT4(x7, wv);
    }
#pragma unroll
    for (int s = 1; s <= 4; s <<= 1) {
        a0 += __shfl_xor(a0, s); a1 += __shfl_xor(a1, s);
        a2 += __shfl_xor(a2, s); a3 += __shfl_xor(a3, s);
        a4 += __shfl_xor(a4, s); a5 += __shfl_xor(a5, s);
        a6 += __shfl_xor(a6, s); a7 += __shfl_xor(a7, s);
    }

    if (part == 0) {
        float sv[8] = {a0, a1, a2, a3, a4, a5, a6, a7};
        if (out < 16) {
            const float ae = -expf(A_log[h]);
            const float db = dt_bias[h];
#pragma unroll
            for (int r = 0; r < 8; ++r) {
                float v = sv[r] + db;
                float sp = (v > 20.0f) ? v : log1pf(expf(v));
                g[((size_t)r0 + r) * HH + h] = ae * sp;
            }
        } else {
#pragma unroll
            for (int r = 0; r < 8; ++r)
                beta[((size_t)r0 + r) * HH + h] = sigmoidf_(sv[r]);
        }
    }
}

// ---------------------------------------------------------------------------
// Phase A1: stage normalized q,k (conv+silu+l2norm) and cumsum(g). (unchanged)
// ---------------------------------------------------------------------------
__global__ __launch_bounds__(64) void stage_k(const float* __restrict__ q_pre,
                                              const float* __restrict__ k_pre,
                                              const float* __restrict__ cq,
                                              const float* __restrict__ ck,
                                              const float* __restrict__ g,
                                              float* __restrict__ Qc,
                                              float* __restrict__ Kc,
                                              float* __restrict__ bcum) {
    const int blk = blockIdx.x;
    const int bh = blk >> 5;
    const int c = blk & 31;
    const int b = bh >> 4;
    const int h = bh & 15;
    const int lane = threadIdx.x;
    const int ch = h * DK + lane;

    const float4 wq4 = *(const float4*)&cq[ch * 4];
    const float4 wk4 = *(const float4*)&ck[ch * 4];

    float qw0 = 0, qw1 = 0, qw2 = 0, kw0 = 0, kw1 = 0, kw2 = 0;
    {
        const int t0 = c * CL;
        if (t0 - 3 >= 0) { size_t bi = ((size_t)b * TT + t0 - 3) * HD + ch; qw0 = q_pre[bi]; kw0 = k_pre[bi]; }
        if (t0 - 2 >= 0) { size_t bi = ((size_t)b * TT + t0 - 2) * HD + ch; qw1 = q_pre[bi]; kw1 = k_pre[bi]; }
        if (t0 - 1 >= 0) { size_t bi = ((size_t)b * TT + t0 - 1) * HD + ch; qw2 = q_pre[bi]; kw2 = k_pre[bi]; }
    }
    float* Qo = Qc + (size_t)blk * 4096;
    float* Ko = Kc + (size_t)blk * 4096;

    for (int tt = 0; tt < CL; ++tt) {
        const int t = c * CL + tt;
        const size_t bi = ((size_t)b * TT + t) * HD + ch;
        const float qc_ = q_pre[bi];
        const float kc_ = k_pre[bi];
        float qa = qw0 * wq4.x + qw1 * wq4.y + qw2 * wq4.z + qc_ * wq4.w;
        float ka = kw0 * wk4.x + kw1 * wk4.y + kw2 * wk4.z + kc_ * wk4.w;
        qw0 = qw1; qw1 = qw2; qw2 = qc_;
        kw0 = kw1; kw1 = kw2; kw2 = kc_;
        qa = siluf_(qa);
        ka = siluf_(ka);
        float qs2 = qa * qa, ks2 = ka * ka;
#pragma unroll
        for (int s = 32; s > 0; s >>= 1) {
            qs2 += __shfl_xor(qs2, s);
            ks2 += __shfl_xor(ks2, s);
        }
        Qo[tt * 64 + lane] = qa * rsqrtf(qs2 + 1e-6f) * 0.125f;
        Ko[tt * 64 + lane] = ka * rsqrtf(ks2 + 1e-6f);
    }

    float cum = g[((size_t)b * TT + c * CL + lane) * HH + h];
#pragma unroll
    for (int s = 1; s < 64; s <<= 1) {
        float u = __shfl_up(cum, s);
        if (lane >= s) cum += u;
    }
    bcum[(size_t)blk * 64 + lane] = cum;
}

// ---------------------------------------------------------------------------
// Phase A2 (R5): scratch-free blocked triangular solve (unchanged)
// ---------------------------------------------------------------------------
__global__ __launch_bounds__(256) void prep_k(const float* __restrict__ Kc,
                                              const float* __restrict__ v_pre,
                                              const float* __restrict__ cv,
                                              const float* __restrict__ bcum,
                                              const float* __restrict__ bbuf,
                                              float* __restrict__ Wv,
                                              float* __restrict__ Wk) {
    __shared__ __align__(16) float k_s[CL * PAD];
    __shared__ __align__(16) float wv_s[CL * PAD];
    __shared__ __align__(16) float wk_s[CL * PAD];
    __shared__ __align__(16) float A_s[CL * PAD];
    __shared__ float T_s[4][16 * 17];
    __shared__ float b_s[CL], beta_s[CL], bk_s[CL];

    const int blk = blockIdx.x;
    const int bh = blk >> 5;
    const int c = blk & 31;
    const int b = bh >> 4;
    const int h = bh & 15;
    const int tid = threadIdx.x;

    if (tid < 64) {
        float bv = bcum[(size_t)blk * 64 + tid];
        float be = bbuf[((size_t)b * TT + c * CL + tid) * HH + h];
        b_s[tid] = bv;
        beta_s[tid] = be;
        bk_s[tid] = be * __expf(bv);
    }
    __syncthreads();

    {
        const float4* Kg = (const float4*)(Kc + (size_t)blk * 4096);
#pragma unroll
        for (int i = 0; i < 4; ++i) {
            int f = tid + i * 256;
            int t = f >> 4;
            int d = t * PAD + (f & 15) * 4;
            float4 kv = Kg[f];
            *(float4*)&k_s[d] = kv;
            float sk = bk_s[t];
            *(float4*)&wk_s[d] = make_float4(kv.x * sk, kv.y * sk, kv.z * sk, kv.w * sk);
        }
    }

    {
        const int lane = tid & 63;
        const int q4 = tid >> 6;
        const int ch = h * DK + lane;
        const float4 wv4 = *(const float4*)&cv[ch * 4];
        const int T0 = c * CL + q4 * 16;
        float w0 = 0, w1 = 0, w2 = 0;
        if (T0 - 3 >= 0) w0 = v_pre[((size_t)b * TT + T0 - 3) * HD + ch];
        if (T0 - 2 >= 0) w1 = v_pre[((size_t)b * TT + T0 - 2) * HD + ch];
        if (T0 - 1 >= 0) w2 = v_pre[((size_t)b * TT + T0 - 1) * HD + ch];
#pragma unroll 1
        for (int i = 0; i < 16; ++i) {
            const int t = T0 + i;
            const float vc_ = v_pre[((size_t)b * TT + t) * HD + ch];
            float va = w0 * wv4.x + w1 * wv4.y + w2 * wv4.z + vc_ * wv4.w;
            w0 = w1; w1 = w2; w2 = vc_;
            va = siluf_(va);
            wv_s[(q4 * 16 + i) * PAD + lane] = va * beta_s[q4 * 16 + i];
        }
    }
    __syncthreads();

    {
        const int t0 = (tid >> 4) * 4, s0 = (tid & 15) * 4;
        float acc[4][4] = {};
        for (int kk = 0; kk < 64; kk += 4) {
            float4 ta0 = *(const float4*)&k_s[(t0 + 0) * PAD + kk];
            float4 ta1 = *(const float4*)&k_s[(t0 + 1) * PAD + kk];
            float4 ta2 = *(const float4*)&k_s[(t0 + 2) * PAD + kk];
            float4 ta3 = *(const float4*)&k_s[(t0 + 3) * PAD + kk];
            float4 sb0 = *(const float4*)&k_s[(s0 + 0) * PAD + kk];
            float4 sb1 = *(const float4*)&k_s[(s0 + 1) * PAD + kk];
            float4 sb2 = *(const float4*)&k_s[(s0 + 2) * PAD + kk];
            float4 sb3 = *(const float4*)&k_s[(s0 + 3) * PAD + kk];
            acc[0][0] += DOT4(ta0, sb0); acc[0][1] += DOT4(ta0, sb1);
            acc[0][2] += DOT4(ta0, sb2); acc[0][3] += DOT4(ta0, sb3);
            acc[1][0] += DOT4(ta1, sb0); acc[1][1] += DOT4(ta1, sb1);
            acc[1][2] += DOT4(ta1, sb2); acc[1][3] += DOT4(ta1, sb3);
            acc[2][0] += DOT4(ta2, sb0); acc[2][1] += DOT4(ta2, sb1);
            acc[2][2] += DOT4(ta2, sb2); acc[2][3] += DOT4(ta2, sb3);
            acc[3][0] += DOT4(ta3, sb0); acc[3][1] += DOT4(ta3, sb1);
            acc[3][2] += DOT4(ta3, sb2); acc[3][3] += DOT4(ta3, sb3);
        }
        __syncthreads();
#pragma unroll
        for (int i = 0; i < 4; ++i)
#pragma unroll
            for (int j = 0; j < 4; ++j) {
                const int t = t0 + i, s = s0 + j;
                A_s[t * PAD + s] = (s < t) ? acc[i][j] * beta_s[t] * __expf(b_s[t] - b_s[s]) : 0.0f;
            }
    }
    __syncthreads();

    if (tid < 64) {
        const int d = tid >> 4;
        const int col = tid & 15;
        const int base = d * 16;
        float tcol[16];
#pragma unroll
        for (int s = 0; s < 16; ++s) tcol[s] = (s == col) ? 1.0f : 0.0f;
#pragma unroll
        for (int t = 1; t < 16; ++t) {
            float a = 0.0f;
#pragma unroll
            for (int s = 0; s < 16; ++s)
                if (s < t) a += A_s[(base + t) * PAD + base + s] * tcol[s];
            tcol[t] -= a;
        }
#pragma unroll
        for (int t = 0; t < 16; ++t) T_s[d][t * 17 + col] = tcol[t];
    }
    __syncthreads();

    {
        const int r = tid >> 4;
        const int cg = tid & 15;
        float* Wc = (cg < 8) ? wv_s : wk_s;
        const int cc = (cg & 7) * 8;

        for (int tb = 0; tb < 4; ++tb) {
            const int t = tb * 16 + r;
            if (tb > 0) {
                float4 lo = *(const float4*)&Wc[t * PAD + cc];
                float4 hi = *(const float4*)&Wc[t * PAD + cc + 4];
#pragma unroll 4
                for (int s = 0; s < tb * 16; ++s) {
                    const float a = A_s[t * PAD + s];
                    float4 wlo = *(const float4*)&Wc[s * PAD + cc];
                    float4 whi = *(const float4*)&Wc[s * PAD + cc + 4];
                    lo.x -= a * wlo.x; lo.y -= a * wlo.y; lo.z -= a * wlo.z; lo.w -= a * wlo.w;
                    hi.x -= a * whi.x; hi.y -= a * whi.y; hi.z -= a * whi.z; hi.w -= a * whi.w;
                }
                *(float4*)&Wc[t * PAD + cc] = lo;
                *(float4*)&Wc[t * PAD + cc + 4] = hi;
            }
            __syncthreads();
            float4 alo = make_float4(0, 0, 0, 0);
            float4 ahi = make_float4(0, 0, 0, 0);
#pragma unroll 4
            for (int s = 0; s < 16; ++s) {
                const float tv = T_s[tb][r * 17 + s];
                float4 wlo = *(const float4*)&Wc[(tb * 16 + s) * PAD + cc];
                float4 whi = *(const float4*)&Wc[(tb * 16 + s) * PAD + cc + 4];
                alo.x += tv * wlo.x; alo.y += tv * wlo.y; alo.z += tv * wlo.z; alo.w += tv * wlo.w;
                ahi.x += tv * whi.x; ahi.y += tv * whi.y; ahi.z += tv * whi.z; ahi.w += tv * whi.w;
            }
            __syncthreads();
            *(float4*)&Wc[t * PAD + cc] = alo;
            *(float4*)&Wc[t * PAD + cc + 4] = ahi;
            __syncthreads();
        }
    }

    float4* Wvg = (float4*)(Wv + (size_t)blk * 4096);
    float4* Wkg = (float4*)(Wk + (size_t)blk * 4096);
#pragma unroll
    for (int i = 0; i < 4; ++i) {
        int f = tid + i * 256;
        int d = (f >> 4) * PAD + (f & 15) * 4;
        Wvg[f] = *(float4*)&wv_s[d];
        Wkg[f] = *(float4*)&wk_s[d];
    }
}

// ---------------------------------------------------------------------------
// Phase B1: chunk-transition operators A_c, B_c.
// R11: A is now written in PANEL-TRANSPOSED layout for hrec_k's direct
// global_load_lds staging:  Ag[p*256 + k*4 + c] = A_logical[k][4p+c].
// (B layout unchanged — hrec reads it per-lane as before.)
// ---------------------------------------------------------------------------
__global__ __launch_bounds__(256) void ab_k(const float* __restrict__ Kc,
                                            const float* __restrict__ Wv,
                                            const float* __restrict__ Wk,
                                            const float* __restrict__ bcum,
                                            float* __restrict__ Ab,
                                            float* __restrict__ Bb) {
    __shared__ __align__(16) float kt_s[CL * PAD];
    __shared__ __align__(16) float wk_s[CL * PAD];
    __shared__ __align__(16) float wv_s[CL * PAD];
    __shared__ float e_s[CL];
    __shared__ float ebC_s;

    const int blk = blockIdx.x;
    const int tid = threadIdx.x;

    if (tid < 64) {
        float bC = bcum[(size_t)blk * 64 + 63];
        e_s[tid] = __expf(bC - bcum[(size_t)blk * 64 + tid]);
        if (tid == 63) ebC_s = __expf(bC);
    }
    __syncthreads();

    {
        const float4* Kg = (const float4*)(Kc + (size_t)blk * 4096);
        const float4* Wkg = (const float4*)(Wk + (size_t)blk * 4096);
        const float4* Wvg = (const float4*)(Wv + (size_t)blk * 4096);
#pragma unroll
        for (int i = 0; i < 4; ++i) {
            int f = tid + i * 256;
            int t = f >> 4;
            int d = t * PAD + (f & 15) * 4;
            float4 kv = Kg[f];
            float e = e_s[t];
            *(float4*)&kt_s[d] = make_float4(kv.x * e, kv.y * e, kv.z * e, kv.w * e);
            *(float4*)&wk_s[d] = Wkg[f];
            *(float4*)&wv_s[d] = Wvg[f];
        }
    }
    __syncthreads();

    const int k0 = (tid >> 4) * 4, m0 = (tid & 15) * 4;
    float aA[4][4] = {};
    float aB[4][4] = {};
    for (int ss = 0; ss < 64; ss += 4) {
        float4 kf0 = *(const float4*)&kt_s[(ss + 0) * PAD + k0];
        float4 kf1 = *(const float4*)&kt_s[(ss + 1) * PAD + k0];
        float4 kf2 = *(const float4*)&kt_s[(ss + 2) * PAD + k0];
        float4 kf3 = *(const float4*)&kt_s[(ss + 3) * PAD + k0];
        float4 wa0 = *(const float4*)&wk_s[(ss + 0) * PAD + m0];
        float4 wa1 = *(const float4*)&wk_s[(ss + 1) * PAD + m0];
        float4 wa2 = *(const float4*)&wk_s[(ss + 2) * PAD + m0];
        float4 wa3 = *(const float4*)&wk_s[(ss + 3) * PAD + m0];
        float4 wb0 = *(const float4*)&wv_s[(ss + 0) * PAD + m0];
        float4 wb1 = *(const float4*)&wv_s[(ss + 1) * PAD + m0];
        float4 wb2 = *(const float4*)&wv_s[(ss + 2) * PAD + m0];
        float4 wb3 = *(const float4*)&wv_s[(ss + 3) * PAD + m0];
        OUT16(aA, kf0, wa0); OUT16(aA, kf1, wa1); OUT16(aA, kf2, wa2); OUT16(aA, kf3, wa3);
        OUT16(aB, kf0, wb0); OUT16(aB, kf1, wb1); OUT16(aB, kf2, wb2); OUT16(aB, kf3, wb3);
    }

    const float ebC = ebC_s;
    float* Ag = Ab + (size_t)blk * 4096;
    float* Bg = Bb + (size_t)blk * 4096;
    const int p = tid & 15;   // panel index = m0>>2
#pragma unroll
    for (int i = 0; i < 4; ++i) {
        const int kk = k0 + i;
        float4 av = make_float4(-aA[i][0], -aA[i][1], -aA[i][2], -aA[i][3]);
        if (kk - m0 == 0) av.x += ebC;
        if (kk - m0 == 1) av.y += ebC;
        if (kk - m0 == 2) av.z += ebC;
        if (kk - m0 == 3) av.w += ebC;
        *(float4*)&Ag[p * 256 + kk * 4] = av;   // panel-transposed (R11)
        *(float4*)&Bg[kk * 64 + m0] = make_float4(aB[i][0], aB[i][1], aB[i][2], aB[i][3]);
    }
}

// ---------------------------------------------------------------------------
// Phase B2 (R11): serial chunk recurrence h' = A_c h + B_c.
// Latency-bound before: VGPR=80 proved the register A-double-buffer collapsed
// -> every chunk ate full L2/L3 load latency serially, plus 2 barrier drains
// per chunk (in a SINGLE-WAVE block). Now:
//   - A staged to LDS via global_load_lds (zero VGPR cost, cannot collapse),
//     double-buffered; counted s_waitcnt vmcnt(18) keeps the next chunk's
//     17 loads in flight across the whole compute (never drain to 0).
//   - A stored panel-transposed by ab_k so staging is linear+coalesced and
//     ds_read_b128 at [m4*256 + k*4] is lane-stride-16B = bank-conflict-free.
//   - No __syncthreads at all (1 wave/block); one lgkmcnt(0) after the h_s
//     update as cross-iteration RAW insurance.
// ---------------------------------------------------------------------------
__global__ __launch_bounds__(64) void hrec_k(const float* __restrict__ Ab,
                                             const float* __restrict__ Bb,
                                             float* __restrict__ Hst) {
    const int blk = blockIdx.x;
    const int bh = blk & 31;          // vs-major: same-bh blocks -> same XCD
    const int vs = blk >> 5;          // 0..VS-1
    const int k = threadIdx.x;

    __shared__ __align__(16) float A_lds[2][4096];
    __shared__ __align__(16) float h_s[4][64];

#pragma unroll
    for (int j = 0; j < 4; ++j) h_s[j][k] = 0.0f;
    float h0 = 0, h1 = 0, h2 = 0, h3 = 0;

    const float* Abase = Ab + (size_t)bh * NC * 4096;
    const float* Bbase = Bb + (size_t)bh * NC * 4096 + k * 64 + vs * 4;
    float* Hbase = Hst + (size_t)bh * NC * 4096 + k * 64 + vs * 4;

    // prologue: stage A(0) into buf0, load B(0) to register
#pragma unroll
    for (int i = 0; i < 16; ++i)
        __builtin_amdgcn_global_load_lds((const GAS unsigned int*)(Abase + i * 256 + k * 4),
                                         (LAS unsigned int*)&A_lds[0][i * 256], 16, 0, 0);
    float4 bn = *(const float4*)&Bbase[0];

    const float* Acur = &A_lds[0][0];
    float* Anxt = &A_lds[1][0];

#pragma unroll 1
    for (int c = 0; c < NC; ++c) {
        float4 b0 = bn;

        // chunk-start state (pre-update); fire-and-forget store
        *(float4*)&Hbase[(size_t)c * 4096] = make_float4(h0, h1, h2, h3);

        if (c + 1 < NC) {
            // prefetch A(c+1) -> other LDS buffer, B(c+1) -> register
            const float* An = Abase + (size_t)(c + 1) * 4096;
#pragma unroll
            for (int i = 0; i < 16; ++i)
                __builtin_amdgcn_global_load_lds((const GAS unsigned int*)(An + i * 256 + k * 4),
                                                 (LAS unsigned int*)&Anxt[i * 256], 16, 0, 0);
            bn = *(const float4*)&Bbase[(size_t)(c + 1) * 4096];
            // leave the 18 newest (store + 16 A-lds + 1 B) in flight;
            // everything older (A(c) staging, B(c)) is then complete.
            asm volatile("s_waitcnt vmcnt(18)" ::: "memory");
        } else {
            asm volatile("s_waitcnt vmcnt(1)" ::: "memory");
        }
        __builtin_amdgcn_sched_barrier(0);

        // h' = A h + B   (A row k from LDS, h broadcast from LDS)
        float a0 = b0.x, a1 = b0.y, a2 = b0.z, a3 = b0.w;
#pragma unroll
        for (int m4 = 0; m4 < 16; ++m4) {
            float4 av = *(const float4*)&Acur[m4 * 256 + k * 4];
            float4 hv0 = *(const float4*)&h_s[0][m4 * 4];
            float4 hv1 = *(const float4*)&h_s[1][m4 * 4];
            float4 hv2 = *(const float4*)&h_s[2][m4 * 4];
            float4 hv3 = *(const float4*)&h_s[3][m4 * 4];
            a0 += DOT4(av, hv0); a1 += DOT4(av, hv1);
            a2 += DOT4(av, hv2); a3 += DOT4(av, hv3);
        }
        h0 = a0; h1 = a1; h2 = a2; h3 = a3;
        h_s[0][k] = h0; h_s[1][k] = h1; h_s[2][k] = h2; h_s[3][k] = h3;
        // single wave: DS is in-order per wave; cheap insurance for the
        // cross-iteration RAW on h_s (no s_barrier needed).
        asm volatile("s_waitcnt lgkmcnt(0)" ::: "memory");

        const float* t = Acur; Acur = Anxt; Anxt = (float*)t;
    }
}

// ---------------------------------------------------------------------------
// Phase B3: W_c = Wv_c - Wk_c h0_c (unchanged)
// ---------------------------------------------------------------------------
__global__ __launch_bounds__(256) void wfix_k(const float* __restrict__ Wk,
                                              const float* __restrict__ Hst,
                                              float* __restrict__ Wio) {
    __shared__ __align__(16) float wk_s[CL * PAD];
    __shared__ __align__(16) float h_s[CL * PAD];

    const int blk = blockIdx.x;
    const int tid = threadIdx.x;

    {
        const float4* Wkg = (const float4*)(Wk + (size_t)blk * 4096);
        const float4* Hg = (const float4*)(Hst + (size_t)blk * 4096);
#pragma unroll
        for (int i = 0; i < 4; ++i) {
            int f = tid + i * 256;
            int d = (f >> 4) * PAD + (f & 15) * 4;
            *(float4*)&wk_s[d] = Wkg[f];
            *(float4*)&h_s[d] = Hg[f];
        }
    }
    __syncthreads();

    const int t0 = (tid >> 4) * 4, v0 = (tid & 15) * 4;
    float* Wg = Wio + (size_t)blk * 4096;

    float acc[4][4];
#pragma unroll
    for (int i = 0; i < 4; ++i) {
        float4 wv = *(const float4*)&Wg[(t0 + i) * 64 + v0];
        acc[i][0] = wv.x; acc[i][1] = wv.y; acc[i][2] = wv.z; acc[i][3] = wv.w;
    }
    for (int kk = 0; kk < 64; kk += 4) {
        float4 wa0 = *(const float4*)&wk_s[(t0 + 0) * PAD + kk];
        float4 wa1 = *(const float4*)&wk_s[(t0 + 1) * PAD + kk];
        float4 wa2 = *(const float4*)&wk_s[(t0 + 2) * PAD + kk];
        float4 wa3 = *(const float4*)&wk_s[(t0 + 3) * PAD + kk];
        float4 hb0 = *(const float4*)&h_s[(kk + 0) * PAD + v0];
        float4 hb1 = *(const float4*)&h_s[(kk + 1) * PAD + v0];
        float4 hb2 = *(const float4*)&h_s[(kk + 2) * PAD + v0];
        float4 hb3 = *(const float4*)&h_s[(kk + 3) * PAD + v0];
        WSUB(x, hb0); WSUB(y, hb1); WSUB(z, hb2); WSUB(w, hb3);
    }
#pragma unroll
    for (int i = 0; i < 4; ++i)
        *(float4*)&Wg[(t0 + i) * 64 + v0] =
            make_float4(acc[i][0], acc[i][1], acc[i][2], acc[i][3]);
}

// ---------------------------------------------------------------------------
// Phase C (R7): scratch-free + PAD-strided LDS (unchanged)
// ---------------------------------------------------------------------------
__global__ __launch_bounds__(256) void out_k(const float* __restrict__ Qc,
                                             const float* __restrict__ Kc,
                                             const float* __restrict__ Wb_,
                                             const float* __restrict__ Hst,
                                             const float* __restrict__ bcum,
                                             float* __restrict__ o_scan) {
    __shared__ __align__(16) float q_s[CL * PAD];
    __shared__ __align__(16) float s_s[CL * PAD];   // K, then S
    __shared__ __align__(16) float h_s[CL * PAD];
    __shared__ __align__(16) float w_s[CL * PAD];
    __shared__ float b_s[64];

    const int blk = blockIdx.x;
    const int bh = blk >> 5;
    const int c = blk & 31;
    const int b = bh >> 4;
    const int h = bh & 15;
    const int tid = threadIdx.x;

    if (tid < 64) b_s[tid] = bcum[(size_t)blk * 64 + tid];
    {
        const float4* Qg = (const float4*)(Qc + (size_t)blk * 4096);
        const float4* Kg = (const float4*)(Kc + (size_t)blk * 4096);
        const float4* Hg = (const float4*)(Hst + (size_t)blk * 4096);
        const float4* Wg = (const float4*)(Wb_ + (size_t)blk * 4096);
#pragma unroll
        for (int i = 0; i < 4; ++i) {
            int f = tid + i * 256;
            int d = (f >> 4) * PAD + (f & 15) * 4;
            *(float4*)&q_s[d] = Qg[f];
            *(float4*)&s_s[d] = Kg[f];
            *(float4*)&h_s[d] = Hg[f];
            *(float4*)&w_s[d] = Wg[f];
        }
    }
    __syncthreads();

    // Phase 1: S = (Q K^T) ⊙ exp(b_t - b_s) [s<=t], overwrite s_s
    {
        const int t0 = (tid >> 4) * 4, s0 = (tid & 15) * 4;
        float acc[4][4] = {};
        for (int kk = 0; kk < 64; kk += 4) {
            float4 ta0 = *(const float4*)&q_s[(t0 + 0) * PAD + kk];
            float4 ta1 = *(const float4*)&q_s[(t0 + 1) * PAD + kk];
            float4 ta2 = *(const float4*)&q_s[(t0 + 2) * PAD + kk];
            float4 ta3 = *(const float4*)&q_s[(t0 + 3) * PAD + kk];
            float4 sb0 = *(const float4*)&s_s[(s0 + 0) * PAD + kk];
            float4 sb1 = *(const float4*)&s_s[(s0 + 1) * PAD + kk];
            float4 sb2 = *(const float4*)&s_s[(s0 + 2) * PAD + kk];
            float4 sb3 = *(const float4*)&s_s[(s0 + 3) * PAD + kk];
            acc[0][0] += DOT4(ta0, sb0); acc[0][1] += DOT4(ta0, sb1);
            acc[0][2] += DOT4(ta0, sb2); acc[0][3] += DOT4(ta0, sb3);
            acc[1][0] += DOT4(ta1, sb0); acc[1][1] += DOT4(ta1, sb1);
            acc[1][2] += DOT4(ta1, sb2); acc[1][3] += DOT4(ta1, sb3);
            acc[2][0] += DOT4(ta2, sb0); acc[2][1] += DOT4(ta2, sb1);
            acc[2][2] += DOT4(ta2, sb2); acc[2][3] += DOT4(ta2, sb3);
            acc[3][0] += DOT4(ta3, sb0); acc[3][1] += DOT4(ta3, sb1);
            acc[3][2] += DOT4(ta3, sb2); acc[3][3] += DOT4(ta3, sb3);
        }
        __syncthreads();   // all Q,K reads done before overwrite
#pragma unroll
        for (int i = 0; i < 4; ++i)
#pragma unroll
            for (int j = 0; j < 4; ++j) {
                const int t = t0 + i, s = s0 + j;
                s_s[t * PAD + s] = (s <= t) ? acc[i][j] * __expf(b_s[t] - b_s[s]) : 0.0f;
            }
    }
    // scale q rows by e^{b_t}
#pragma unroll
    for (int i = 0; i < 16; ++i) {
        const int e = tid + i * 256;
        const int t = e >> 6;
        q_s[t * PAD + (e & 63)] *= __expf(b_s[t]);
    }
    __syncthreads();

    // Phase 2: O = S @ W + Qs @ H
    {
        const int t0 = (tid >> 4) * 4, v0 = (tid & 15) * 4;
        float acc[4][4] = {};
        for (int ss = 0; ss < 64; ss += 4) {
            float4 sa0 = *(const float4*)&s_s[(t0 + 0) * PAD + ss];
            float4 sa1 = *(const float4*)&s_s[(t0 + 1) * PAD + ss];
            float4 sa2 = *(const float4*)&s_s[(t0 + 2) * PAD + ss];
            float4 sa3 = *(const float4*)&s_s[(t0 + 3) * PAD + ss];
            float4 wb0 = *(const float4*)&w_s[(ss + 0) * PAD + v0];
            float4 wb1 = *(const float4*)&w_s[(ss + 1) * PAD + v0];
            float4 wb2 = *(const float4*)&w_s[(ss + 2) * PAD + v0];
            float4 wb3 = *(const float4*)&w_s[(ss + 3) * PAD + v0];
            ACC16(x, wb0); ACC16(y, wb1); ACC16(z, wb2); ACC16(w, wb3);
        }
        for (int kk = 0; kk < 64; kk += 4) {
            float4 sa0 = *(const float4*)&q_s[(t0 + 0) * PAD + kk];
            float4 sa1 = *(const float4*)&q_s[(t0 + 1) * PAD + kk];
            float4 sa2 = *(const float4*)&q_s[(t0 + 2) * PAD + kk];
            float4 sa3 = *(const float4*)&q_s[(t0 + 3) * PAD + kk];
            float4 wb0 = *(const float4*)&h_s[(kk + 0) * PAD + v0];
            float4 wb1 = *(const float4*)&h_s[(kk + 1) * PAD + v0];
            float4 wb2 = *(const float4*)&h_s[(kk + 2) * PAD + v0];
            float4 wb3 = *(const float4*)&h_s[(kk + 3) * PAD + v0];
            ACC16(x, wb0); ACC16(y, wb1); ACC16(z, wb2); ACC16(w, wb3);
        }
#pragma unroll
        for (int i = 0; i < 4; ++i) {
            const int t = c * CL + t0 + i;
            *(float4*)&o_scan[(((size_t)b * TT + t) * HH + h) * DK + v0] =
                make_float4(acc[i][0], acc[i][1], acc[i][2], acc[i][3]);
        }
    }
}

// ---------------------------------------------------------------------------
// Gated RMSNorm -> bf16 output (unchanged)
// ---------------------------------------------------------------------------
__global__ __launch_bounds__(256) void gnorm_k(const float* __restrict__ o_scan,
                                               const float* __restrict__ gate,
                                               const float* __restrict__ rms_w,
                                               unsigned short* __restrict__ o2) {
    const int tid = threadIdx.x;
    const int grp = tid >> 6;
    const int lane = tid & 63;
    const int bth = blockIdx.x * 4 + grp;
    const int h = bth & 15;
    const int row = bth >> 4;

    float ov = o_scan[(size_t)bth * DK + lane];
    float s = ov * ov;
#pragma unroll
    for (int sh = 32; sh > 0; sh >>= 1) s += __shfl_xor(s, sh);
    float r = rsqrtf(s * (1.0f / 64.0f) + 1e-5f);

    float gt = gate[(size_t)row * HD + h * DK + lane];
    o2[(size_t)row * HD + h * DK + lane] = f2bf(ov * r * rms_w[lane] * siluf_(gt));
}

// ---------------------------------------------------------------------------
extern "C" void kernel_launch(void* const* d_in, const int* in_sizes, int n_in,
                              void* d_out, int out_size, void* d_ws, size_t ws_size,
                              hipStream_t stream) {
    (void)in_sizes; (void)n_in; (void)out_size; (void)ws_size;

    const float* x       = (const float*)d_in[0];
    const float* Wq      = (const float*)d_in[1];
    const float* Wk_     = (const float*)d_in[2];
    const float* Wv_     = (const float*)d_in[3];
    const float* Wa      = (const float*)d_in[4];
    const float* Wb      = (const float*)d_in[5];
    const float* Wg      = (const float*)d_in[6];
    const float* Wo      = (const float*)d_in[7];
    const float* conv_q  = (const float*)d_in[8];
    const float* conv_k  = (const float*)d_in[9];
    const float* conv_v  = (const float*)d_in[10];
    const float* A_log   = (const float*)d_in[11];
    const float* dt_bias = (const float*)d_in[12];
    const float* rms_w   = (const float*)d_in[13];
    float* out = (float*)d_out;

    float* ws = (float*)d_ws;
    const size_t NTOK = (size_t)BB * TT;     // 4096
    const size_t BIG = NTOK * HD;            // 4 Mi floats

    float* q_pre = ws + 0 * BIG;
    float* k_pre = ws + 1 * BIG;
    float* v_pre = ws + 2 * BIG;
    float* gatep = ws + 3 * BIG;
    float* Qc    = ws + 4 * BIG;
    float* Kc    = ws + 5 * BIG;
    float* gbuf  = ws + 6 * BIG;
    float* bbuf  = gbuf + NTOK * HH;
    float* bcumb = bbuf + NTOK * HH;

    // bf16 buffers after the fp32 region (wqt..wgt contiguous = fused B matrix)
    unsigned short* xb  = (unsigned short*)(bcumb + NTOK * HH);
    unsigned short* wqt = xb + (size_t)NTOK * DD;
    unsigned short* wkt = wqt + (size_t)DD * HD;
    unsigned short* wvt = wkt + (size_t)DD * HD;
    unsigned short* wgt = wvt + (size_t)DD * HD;
    unsigned short* wot = wgt + (size_t)DD * HD;

    // fp32 buffers after bf16 region: Bb + Hst (32 MB) + Wab_t (128 KB)
    float* Bbuf = (float*)(wot + (size_t)DD * HD);
    float* HstB = Bbuf + BIG;
    float* Wabt = HstB + BIG;

    // aliases (stream-ordered lifetimes):
    float* Wvb    = q_pre;   // prep_k out; wfix_k rewrites in place to W
    float* Wkb    = k_pre;
    float* Abuf   = v_pre;   // ab_k out (v_pre dead after prep_k)
    float* o_scan = v_pre;   // out_k out (Abuf dead after hrec_k)
    unsigned short* o2b = (unsigned short*)Qc;

    // casts
    castx_k<<<(int)(NTOK * DD / (256 * 8)), 256, 0, stream>>>(x, xb);
    dim3 tg(16, 16);
    castw_k<<<tg, 256, 0, stream>>>(Wq, wqt);
    castw_k<<<tg, 256, 0, stream>>>(Wk_, wkt);
    castw_k<<<tg, 256, 0, stream>>>(Wv_, wvt);
    castw_k<<<tg, 256, 0, stream>>>(Wg, wgt);
    castw_k<<<tg, 256, 0, stream>>>(Wo, wot);
    tw_k<<<32, 256, 0, stream>>>(Wa, Wb, Wabt);

    // fused QKVG projection: one dispatch, 1024 blocks
    gemm_qkvg_k<<<dim3(32, 32), 256, 0, stream>>>(xb, wqt, q_pre, k_pre, v_pre, gatep);

    gbeta_k<<<(int)(NTOK / 8), 256, 0, stream>>>(x, Wabt, A_log, dt_bias, gbuf, bbuf);

    stage_k<<<BB * HH * NC, 64, 0, stream>>>(q_pre, k_pre, conv_q, conv_k, gbuf,
                                             Qc, Kc, bcumb);

    prep_k<<<BB * HH * NC, 256, 0, stream>>>(Kc, v_pre, conv_v, bcumb, bbuf, Wvb, Wkb);

    // chunked state recurrence, decomposed:
    ab_k<<<BB * HH * NC, 256, 0, stream>>>(Kc, Wvb, Wkb, bcumb, Abuf, Bbuf);
    hrec_k<<<BB * HH * VS, 64, 0, stream>>>(Abuf, Bbuf, HstB);
    wfix_k<<<BB * HH * NC, 256, 0, stream>>>(Wkb, HstB, Wvb);

    out_k<<<BB * HH * NC, 256, 0, stream>>>(Qc, Kc, Wvb, HstB, bcumb, o_scan);

    gnorm_k<<<(int)(NTOK * HH / 4), 256, 0, stream>>>(o_scan, gatep, rms_w, o2b);

    gemm_bf16_k<<<dim3(HD / 128, NTOK / 128), 256, 0, stream>>>(o2b, wot, out,
                                                                (int)NTOK, HD, DD);
}